// Round 4
// baseline (1563.662 us; speedup 1.0000x reference)
//
#include <hip/hip_runtime.h>

// out[b, i*16+j, d, l] = sum_ks s[b,(j-i)&15,l,ks] * t[b,j,l,d-ks], d in [0,125); 0 for d>=125.
// B=32, N=16, L=64, D_in=63, D_out=128. Output 32*256*128*64 fp32 = 256 MB.
//
// v5: t-in-LDS with explicit latency-covering prefetch.
//   Evidence so far: v2 coalesced loads +15us; v3 store vectorization neutral;
//   v4 (t in LDS, naive reads) -65us REGRESSION: ds_read -> 16 dependent FMAs
//   serialized (~150cyc/kt vs 32) under a 128-reg cap.
//   v5 keeps the register win of t-in-LDS but breaks the chain:
//   - t-row (shared by the 4 waves of a block, i = q*4+w) staged in LDS in its
//     ORIGINAL [l][63] layout: stride 63 = -1 mod 32 -> lane l hits bank
//     (kt - l) mod 32 -> 2 lanes/bank = conflict-free broadcast of tl[kt].
//     => no global transpose needed for t; only s is pre-transposed.
//   - double-buffered prefetch in groups of 4 kt: issue 4 independent ds_reads
//     for group g+1, then 64 FMAs (128 cyc) on group g >= 120 cyc LDS latency.
//     All tbuf indices compile-time (g&1 under full unroll) -> no scratch.
//   - registers: sv[63] + acc[16] + tbuf[8] + addr ~ 95-100; __launch_bounds__
//     (256,5) caps at 102 -> 5 waves/SIMD (v3 had 3). LDS 16.1 KB/block.
//   - stores: direct dword, 256 B/instr (v3 showed staging to dwordx4 neutral).
//   1) transpose_s_kernel: s [B,N,L,63] -> [B,N,63,L] in d_ws (~8 MB, ~5us).
//   2) conv_kernel_v5 as above. Fallback to v1 kernel if ws too small.

#define D_IN 63
#define L_DIM 64
#define N_DIM 16
#define DP 128
#define B_DIM 32

// ---------- transpose s: [B,N,L,D_IN] -> [B,N,D_IN,L] ----------
__global__ __launch_bounds__(256) void transpose_s_kernel(
    const float* __restrict__ s, float* __restrict__ so)
{
    const int bn = blockIdx.x;                       // 0..511
    const float* __restrict__ src = s  + (size_t)bn * (L_DIM * D_IN);
    float* __restrict__ dst       = so + (size_t)bn * (L_DIM * D_IN);

    __shared__ float lds[L_DIM * D_IN];              // 16128 B

    for (int f = threadIdx.x; f < L_DIM * D_IN; f += 256)
        lds[f] = src[f];
    __syncthreads();

    // write [D,L]; lds read stride 63 across lanes -> 2 lanes/bank = free
    for (int g = threadIdx.x; g < L_DIM * D_IN; g += 256) {
        const int d = g >> 6;
        const int l = g & 63;
        dst[g] = lds[l * D_IN + d];
    }
}

// ---------- conv: 4 waves share the t-row in LDS ----------
__global__ __launch_bounds__(256, 5) void conv_kernel_v5(
    const float* __restrict__ st,    // transposed s [B,N,63,64]
    const float* __restrict__ t,     // original   t [B,N,64,63]
    float* __restrict__ out)
{
    const int bi = blockIdx.x;           // (b*16 + j)*4 + q
    const int q  = bi & 3;
    const int j  = (bi >> 2) & 15;
    const int b  = bi >> 6;
    const int w  = threadIdx.x >> 6;     // wave 0..3
    const int l  = threadIdx.x & 63;
    const int i  = q * 4 + w;            // 0..15
    const int k  = (j - i) & 15;

    __shared__ float tls[L_DIM * D_IN];  // t-row, original [l][ks] layout, 16128 B

    // cooperative coalesced copy of t-row (b,j)
    {
        const float* __restrict__ trow = t + (size_t)(b * N_DIM + j) * (L_DIM * D_IN);
#pragma unroll
        for (int it = 0; it < 16; ++it) {
            const int f = it * 256 + (int)threadIdx.x;
            if (f < L_DIM * D_IN) tls[f] = trow[f];
        }
    }

    // private s-row, coalesced loads from transposed layout
    const float* __restrict__ srow = st + (size_t)(b * N_DIM + k) * (D_IN * L_DIM) + l;
    float sv[D_IN];
#pragma unroll
    for (int c = 0; c < D_IN; ++c) sv[c] = srow[c * L_DIM];

    __syncthreads();

    const int blk = (b * N_DIM + i) * N_DIM + j;
    float* __restrict__ orow = out + (size_t)blk * (DP * L_DIM) + l;
    const float* __restrict__ tl = &tls[l * D_IN];   // this lane's t row

#pragma unroll
    for (int d0 = 0; d0 < DP; d0 += 16) {
        // kt window with any valid ks = d0+dd-kt: kt in [d0-62, d0+15] clip [0,62]
        const int lo  = (d0 - 62 < 0) ? 0 : (d0 - 62);
        const int hi  = (d0 + 15 > 62) ? 62 : (d0 + 15);   // inclusive
        const int cnt = hi - lo + 1;
        const int NG  = (cnt + 3) >> 2;                    // groups of 4

        float acc[16];
#pragma unroll
        for (int dd = 0; dd < 16; ++dd) acc[dd] = 0.0f;

        float tbuf[2][4];
        // prologue: load group 0
#pragma unroll
        for (int u = 0; u < 4; ++u)
            if (lo + u <= hi) tbuf[0][u] = tl[lo + u];

#pragma unroll
        for (int g = 0; g < 16; ++g) {                    // NG <= 16; guarded below
            if (g < NG) {
                const int cur = g & 1, nxt = cur ^ 1;     // compile-time under unroll
                // prefetch group g+1 (4 independent ds_reads) BEFORE computing g
                if (g + 1 < NG) {
#pragma unroll
                    for (int u = 0; u < 4; ++u) {
                        const int kt = lo + (g + 1) * 4 + u;
                        if (kt <= hi) tbuf[nxt][u] = tl[kt];
                    }
                }
                // 64 FMAs (128 cyc) on group g covers the ~120 cyc LDS latency
#pragma unroll
                for (int u = 0; u < 4; ++u) {
                    const int kt = lo + g * 4 + u;
                    if (kt <= hi) {
                        const float tv = tbuf[cur][u];
#pragma unroll
                        for (int dd = 0; dd < 16; ++dd) {
                            const int ks = d0 + dd - kt;   // compile-time
                            if (ks >= 0 && ks < D_IN)
                                acc[dd] += sv[ks] * tv;
                        }
                    }
                }
            }
        }

        // direct coalesced stores (256 B / instruction)
#pragma unroll
        for (int dd = 0; dd < 16; ++dd)
            orow[(size_t)(d0 + dd) * L_DIM] = acc[dd];
    }
}

// ---------- v1 fallback (no workspace needed) ----------
__global__ __launch_bounds__(64) void conv_kernel_fallback(
    const float* __restrict__ s, const float* __restrict__ t,
    float* __restrict__ out)
{
    const int blk = blockIdx.x;
    const int b  = blk >> 8;
    const int ij = blk & 255;
    const int i  = ij >> 4;
    const int j  = ij & 15;
    const int k  = (j - i) & 15;
    const int l  = threadIdx.x;

    const float* __restrict__ srow = s + ((((size_t)b * N_DIM + k) * L_DIM + l) * D_IN);
    const float* __restrict__ trow = t + ((((size_t)b * N_DIM + j) * L_DIM + l) * D_IN);

    float sv[D_IN], tv[D_IN];
#pragma unroll
    for (int c = 0; c < D_IN; ++c) sv[c] = srow[c];
#pragma unroll
    for (int c = 0; c < D_IN; ++c) tv[c] = trow[c];

    float* __restrict__ orow = out + ((size_t)blk * (DP * L_DIM)) + l;

#pragma unroll
    for (int d0 = 0; d0 < DP; d0 += 16) {
        float acc[16];
#pragma unroll
        for (int dd = 0; dd < 16; ++dd) acc[dd] = 0.0f;
#pragma unroll
        for (int ks = 0; ks < D_IN; ++ks) {
#pragma unroll
            for (int dd = 0; dd < 16; ++dd) {
                const int kt = d0 + dd - ks;
                if (kt >= 0 && kt < D_IN)
                    acc[dd] += sv[ks] * tv[kt];
            }
        }
#pragma unroll
        for (int dd = 0; dd < 16; ++dd)
            orow[(size_t)(d0 + dd) * L_DIM] = acc[dd];
    }
}

extern "C" void kernel_launch(void* const* d_in, const int* in_sizes, int n_in,
                              void* d_out, int out_size, void* d_ws, size_t ws_size,
                              hipStream_t stream) {
    const float* s = (const float*)d_in[0];
    const float* t = (const float*)d_in[1];
    float* out = (float*)d_out;

    const size_t elems = (size_t)B_DIM * N_DIM * L_DIM * D_IN;   // 2,064,384
    const size_t need  = elems * sizeof(float);                  // ~8.3 MB (s only)

    if (d_ws != nullptr && ws_size >= need) {
        float* so = (float*)d_ws;
        hipLaunchKernelGGL(transpose_s_kernel, dim3(B_DIM * N_DIM), dim3(256), 0, stream,
                           s, so);
        // grid: (b, j, quarter) = 32*16*4 = 2048 workgroups x 256 threads
        hipLaunchKernelGGL(conv_kernel_v5, dim3(B_DIM * N_DIM * 4), dim3(256), 0, stream,
                           so, t, out);
    } else {
        hipLaunchKernelGGL(conv_kernel_fallback, dim3(B_DIM * N_DIM * N_DIM), dim3(64), 0, stream,
                           s, t, out);
    }
}

// Round 5
// 392.427 us; speedup vs baseline: 3.9846x; 3.9846x over previous
//
#include <hip/hip_runtime.h>

// out[b, i*16+j, d, l] = sum_ks s[b,(j-i)&15,l,ks] * t[b,j,l,d-ks], d in [0,125); 0 for d>=125.
// B=32, N=16, L=64, D_in=63, D_out=128. Output 32*256*128*64 fp32 = 256 MB.
//
// v6: DIAGNOSTIC ROUND (deliberate ~2x dur regression to surface counters).
//   History: v3 best (conv ~108us vs floors: FMA-issue 26.5us, store-BW 42.6us).
//   All stall hypotheses tested so far failed (loads +15us, stores +-0,
//   LDS-sharing -65us, reg-cap -> total spill -1245us). We have NEVER seen the
//   conv kernel's own counters: at ~108us it is always below the ~175us harness
//   poison fills in the top-5. This round: v3's exact conv with the
//   compute+store body repeated 3x in-kernel (idempotent, output correct),
//   anti-CSE/DSE asm barriers between reps, so the dispatch (~310us) lands
//   top-1 and reports VGPR_Count / VALUBusy / Occupancy / FETCH / WRITE.
//   Decision tree for next round:
//     - VGPR tiny or FETCH >> 200MB  -> v3 was silently spilling; shrink arrays.
//     - VALUBusy >= 55%              -> issue-bound; cut non-FMA VALU overhead.
//     - VALUBusy ~30% & Occupancy<35%-> latency-bound; raise occupancy w/o caps.
//     - WRITE << 800MB               -> stores L2-absorbed; store BW never a cost.

#define D_IN 63
#define L_DIM 64
#define N_DIM 16
#define DP 128
#define B_DIM 32

// ---------- transpose [B,N,L,D_IN] -> [B,N,D_IN,L] ----------
__global__ __launch_bounds__(256) void transpose_kernel(
    const float* __restrict__ s, const float* __restrict__ t,
    float* __restrict__ so, float* __restrict__ to)
{
    const int tile = blockIdx.x;                     // 0..1023 ; first 512 = s, rest = t
    const int bn   = tile & (B_DIM * N_DIM - 1);     // 0..511
    const float* __restrict__ src =
        (tile < B_DIM * N_DIM ? s : t) + (size_t)bn * (L_DIM * D_IN);
    float* __restrict__ dst =
        (tile < B_DIM * N_DIM ? so : to) + (size_t)bn * (L_DIM * D_IN);

    __shared__ float lds[L_DIM * D_IN];              // 16128 B

    for (int f = threadIdx.x; f < L_DIM * D_IN; f += 256)
        lds[f] = src[f];
    __syncthreads();

    // coalesced write of the [D,L] tile; lds read stride 63 across lanes
    // (63 mod 32 = 31 -> at most 2 lanes/bank = free)
    for (int g = threadIdx.x; g < L_DIM * D_IN; g += 256) {
        const int d = g >> 6;        // 0..62
        const int l = g & 63;
        dst[g] = lds[l * D_IN + d];
    }
}

// ---------- conv on transposed inputs, x3 repeat for counter visibility ----------
__global__ __launch_bounds__(64) void conv_kernel_diag(
    const float* __restrict__ st, const float* __restrict__ tt,
    float* __restrict__ out)
{
    const int blk = blockIdx.x;          // b*256 + i*16 + j
    const int b  = blk >> 8;
    const int ij = blk & 255;
    const int i  = ij >> 4;
    const int j  = ij & 15;
    const int k  = (j - i) & 15;
    const int l  = threadIdx.x;          // 0..63

    // transposed layout: element (b,n,c,l) at ((b*16+n)*63 + c)*64 + l
    const float* __restrict__ srow = st + (((size_t)b * N_DIM + k) * D_IN) * L_DIM + l;
    const float* __restrict__ trow = tt + (((size_t)b * N_DIM + j) * D_IN) * L_DIM + l;

    float sv[D_IN], tv[D_IN];
#pragma unroll
    for (int c = 0; c < D_IN; ++c) sv[c] = srow[(size_t)c * L_DIM];  // coalesced
#pragma unroll
    for (int c = 0; c < D_IN; ++c) tv[c] = trow[(size_t)c * L_DIM];  // coalesced

    // per-wave staging tile for store vectorization: 16 rows (d) x 65 cols (l)
    __shared__ float xpose[16 * 65];                 // 4160 B

    float* __restrict__ obase = out + ((size_t)blk * (DP * L_DIM));

    const int rq = l >> 4;               // 0..3
    const int c4 = (l & 15) << 2;        // 0..60 step 4

    for (int rep = 0; rep < 3; ++rep) {
        // opaque-touch sv: the whole FMA DAG depends on it -> no CSE across reps;
        // memory clobber -> rep stores can't be dead-store-eliminated.
#pragma unroll
        for (int c = 0; c < D_IN; ++c) asm volatile("" : "+v"(sv[c]));
        asm volatile("" ::: "memory");

#pragma unroll
        for (int d0 = 0; d0 < DP; d0 += 16) {
            float acc[16];
#pragma unroll
            for (int dd = 0; dd < 16; ++dd) acc[dd] = 0.0f;

#pragma unroll
            for (int ks = 0; ks < D_IN; ++ks) {
#pragma unroll
                for (int dd = 0; dd < 16; ++dd) {
                    const int kt = d0 + dd - ks;           // compile-time constant
                    if (kt >= 0 && kt < D_IN)
                        acc[dd] += sv[ks] * tv[kt];
                }
            }

            // stage acc into LDS: xpose[dd][l] (2 lanes/bank = conflict-free)
#pragma unroll
            for (int dd = 0; dd < 16; ++dd)
                xpose[dd * 65 + l] = acc[dd];

            // single-wave block: DS ops program-ordered; read back transposed
#pragma unroll
            for (int q = 0; q < 4; ++q) {
                const int r = (q << 2) + rq;             // 0..15
                const float4 v = *reinterpret_cast<const float4*>(&xpose[r * 65 + c4]);
                *reinterpret_cast<float4*>(&obase[(size_t)(d0 + r) * L_DIM + c4]) = v;
            }
        }
    }
}

// ---------- v1 fallback (uncoalesced loads) ----------
__global__ __launch_bounds__(64) void conv_kernel_fallback(
    const float* __restrict__ s, const float* __restrict__ t,
    float* __restrict__ out)
{
    const int blk = blockIdx.x;
    const int b  = blk >> 8;
    const int ij = blk & 255;
    const int i  = ij >> 4;
    const int j  = ij & 15;
    const int k  = (j - i) & 15;
    const int l  = threadIdx.x;

    const float* __restrict__ srow = s + ((((size_t)b * N_DIM + k) * L_DIM + l) * D_IN);
    const float* __restrict__ trow = t + ((((size_t)b * N_DIM + j) * L_DIM + l) * D_IN);

    float sv[D_IN], tv[D_IN];
#pragma unroll
    for (int c = 0; c < D_IN; ++c) sv[c] = srow[c];
#pragma unroll
    for (int c = 0; c < D_IN; ++c) tv[c] = trow[c];

    float* __restrict__ orow = out + ((size_t)blk * (DP * L_DIM)) + l;

#pragma unroll
    for (int d0 = 0; d0 < DP; d0 += 16) {
        float acc[16];
#pragma unroll
        for (int dd = 0; dd < 16; ++dd) acc[dd] = 0.0f;
#pragma unroll
        for (int ks = 0; ks < D_IN; ++ks) {
#pragma unroll
            for (int dd = 0; dd < 16; ++dd) {
                const int kt = d0 + dd - ks;
                if (kt >= 0 && kt < D_IN)
                    acc[dd] += sv[ks] * tv[kt];
            }
        }
#pragma unroll
        for (int dd = 0; dd < 16; ++dd)
            orow[(size_t)(d0 + dd) * L_DIM] = acc[dd];
    }
}

extern "C" void kernel_launch(void* const* d_in, const int* in_sizes, int n_in,
                              void* d_out, int out_size, void* d_ws, size_t ws_size,
                              hipStream_t stream) {
    const float* s = (const float*)d_in[0];
    const float* t = (const float*)d_in[1];
    float* out = (float*)d_out;

    const size_t elems = (size_t)B_DIM * N_DIM * L_DIM * D_IN;   // 2,064,384
    const size_t need  = 2 * elems * sizeof(float);              // ~16.5 MB

    if (d_ws != nullptr && ws_size >= need) {
        float* so = (float*)d_ws;
        float* to = so + elems;
        hipLaunchKernelGGL(transpose_kernel, dim3(2 * B_DIM * N_DIM), dim3(256), 0, stream,
                           s, t, so, to);
        hipLaunchKernelGGL(conv_kernel_diag, dim3(B_DIM * N_DIM * N_DIM), dim3(64), 0, stream,
                           so, to, out);
    } else {
        hipLaunchKernelGGL(conv_kernel_fallback, dim3(B_DIM * N_DIM * N_DIM), dim3(64), 0, stream,
                           s, t, out);
    }
}

// Round 6
// 305.697 us; speedup vs baseline: 5.1151x; 1.2837x over previous
//
#include <hip/hip_runtime.h>

// out[b, i*16+j, d, l] = sum_ks s[b,(j-i)&15,l,ks] * t[b,j,l,d-ks], d in [0,125); 0 for d>=125.
// B=32, N=16, L=64, D_in=63, D_out=128. Output 32*256*128*64 fp32 = 256 MB.
//
// v7: occupancy fix with v3's body kept intact.
//   v6 diagnostic (3x-rep) decomposed v3's ~108us conv: compute+store ~37us/rep
//   (near FMA-issue floor 26.5us), LOAD PHASE ~71us, at OccupancyPercent=20%
//   (1.6 waves/SIMD, 1-wave workgroups don't pack). VALUBusy "101%" is the
//   gfx94x formula (2x overstated on SIMD-32) -> true ~50% busy, rest stalls.
//   No spill (VGPR=116, FETCH=36MB). Fix:
//   - 256-thread workgroups = 4 independent waves (w -> i = q*4+w), each wave
//     runs v3's exact per-wave body (own sv/tv regs, own xpose slice, no
//     __syncthreads). VGPR 116 -> 4 waves/SIMD co-resident; NO min-waves cap
//     (v5's cap caused total spill).
//   - blockIdx decode q = blk>>9: the 4 blocks sharing t-row (b,j) are 512
//     apart -> same XCD (512%8==0) -> t-row L2 reuse in the load phase.
//   - stores stay xpose+dwordx4; loads stay coalesced via transposed s,t.
// Fallback to v1 kernel if ws_size < 16.5 MB.

#define D_IN 63
#define L_DIM 64
#define N_DIM 16
#define DP 128
#define B_DIM 32

// ---------- transpose [B,N,L,D_IN] -> [B,N,D_IN,L] ----------
__global__ __launch_bounds__(256) void transpose_kernel(
    const float* __restrict__ s, const float* __restrict__ t,
    float* __restrict__ so, float* __restrict__ to)
{
    const int tile = blockIdx.x;                     // 0..1023 ; first 512 = s, rest = t
    const int bn   = tile & (B_DIM * N_DIM - 1);     // 0..511
    const float* __restrict__ src =
        (tile < B_DIM * N_DIM ? s : t) + (size_t)bn * (L_DIM * D_IN);
    float* __restrict__ dst =
        (tile < B_DIM * N_DIM ? so : to) + (size_t)bn * (L_DIM * D_IN);

    __shared__ float lds[L_DIM * D_IN];              // 16128 B

    for (int f = threadIdx.x; f < L_DIM * D_IN; f += 256)
        lds[f] = src[f];
    __syncthreads();

    // coalesced write of the [D,L] tile; lds read stride 63 across lanes
    // (63 mod 32 = 31 -> at most 2 lanes/bank = free)
    for (int g = threadIdx.x; g < L_DIM * D_IN; g += 256) {
        const int d = g >> 6;        // 0..62
        const int l = g & 63;
        dst[g] = lds[l * D_IN + d];
    }
}

// ---------- conv: 4 independent waves per block, v3 body per wave ----------
__global__ __launch_bounds__(256) void conv_kernel_v7(
    const float* __restrict__ st, const float* __restrict__ tt,
    float* __restrict__ out)
{
    const int raw = blockIdx.x;          // 0..2047
    const int q   = raw >> 9;            // 0..3 ; same (b,j) group 512 apart -> same XCD
    const int bj  = raw & 511;           // b*16 + j
    const int b   = bj >> 4;
    const int j   = bj & 15;
    const int w   = threadIdx.x >> 6;    // wave 0..3
    const int l   = threadIdx.x & 63;    // lane = l
    const int i   = q * 4 + w;           // 0..15
    const int k   = (j - i) & 15;

    // transposed layout: element (b,n,c,l) at ((b*16+n)*63 + c)*64 + l
    const float* __restrict__ srow = st + (((size_t)b * N_DIM + k) * D_IN) * L_DIM + l;
    const float* __restrict__ trow = tt + (((size_t)b * N_DIM + j) * D_IN) * L_DIM + l;

    float sv[D_IN], tv[D_IN];
#pragma unroll
    for (int c = 0; c < D_IN; ++c) sv[c] = srow[(size_t)c * L_DIM];  // coalesced
#pragma unroll
    for (int c = 0; c < D_IN; ++c) tv[c] = trow[(size_t)c * L_DIM];  // coalesced

    // per-wave staging tile (16 x 65), disjoint per wave -> no __syncthreads
    __shared__ float xpose[4][16 * 65];              // 16640 B

    const int blk = (b * N_DIM + i) * N_DIM + j;
    float* __restrict__ obase = out + ((size_t)blk * (DP * L_DIM));
    float* __restrict__ xw = &xpose[w][0];

    const int rq = l >> 4;               // 0..3
    const int c4 = (l & 15) << 2;        // 0..60 step 4

#pragma unroll
    for (int d0 = 0; d0 < DP; d0 += 16) {
        float acc[16];
#pragma unroll
        for (int dd = 0; dd < 16; ++dd) acc[dd] = 0.0f;

#pragma unroll
        for (int ks = 0; ks < D_IN; ++ks) {
#pragma unroll
            for (int dd = 0; dd < 16; ++dd) {
                const int kt = d0 + dd - ks;           // compile-time constant
                if (kt >= 0 && kt < D_IN)
                    acc[dd] += sv[ks] * tv[kt];
            }
        }

        // stage acc into LDS: xw[dd][l] (2 lanes/bank = conflict-free)
#pragma unroll
        for (int dd = 0; dd < 16; ++dd)
            xw[dd * 65 + l] = acc[dd];

        // single-wave dependency: DS ops program-ordered; read back transposed
#pragma unroll
        for (int p = 0; p < 4; ++p) {
            const int r = (p << 2) + rq;             // 0..15
            const float4 v = *reinterpret_cast<const float4*>(&xw[r * 65 + c4]);
            *reinterpret_cast<float4*>(&obase[(size_t)(d0 + r) * L_DIM + c4]) = v;
        }
    }
}

// ---------- v1 fallback (uncoalesced loads) ----------
__global__ __launch_bounds__(64) void conv_kernel_fallback(
    const float* __restrict__ s, const float* __restrict__ t,
    float* __restrict__ out)
{
    const int blk = blockIdx.x;
    const int b  = blk >> 8;
    const int ij = blk & 255;
    const int i  = ij >> 4;
    const int j  = ij & 15;
    const int k  = (j - i) & 15;
    const int l  = threadIdx.x;

    const float* __restrict__ srow = s + ((((size_t)b * N_DIM + k) * L_DIM + l) * D_IN);
    const float* __restrict__ trow = t + ((((size_t)b * N_DIM + j) * L_DIM + l) * D_IN);

    float sv[D_IN], tv[D_IN];
#pragma unroll
    for (int c = 0; c < D_IN; ++c) sv[c] = srow[c];
#pragma unroll
    for (int c = 0; c < D_IN; ++c) tv[c] = trow[c];

    float* __restrict__ orow = out + ((size_t)blk * (DP * L_DIM)) + l;

#pragma unroll
    for (int d0 = 0; d0 < DP; d0 += 16) {
        float acc[16];
#pragma unroll
        for (int dd = 0; dd < 16; ++dd) acc[dd] = 0.0f;
#pragma unroll
        for (int ks = 0; ks < D_IN; ++ks) {
#pragma unroll
            for (int dd = 0; dd < 16; ++dd) {
                const int kt = d0 + dd - ks;
                if (kt >= 0 && kt < D_IN)
                    acc[dd] += sv[ks] * tv[kt];
            }
        }
#pragma unroll
        for (int dd = 0; dd < 16; ++dd)
            orow[(size_t)(d0 + dd) * L_DIM] = acc[dd];
    }
}

extern "C" void kernel_launch(void* const* d_in, const int* in_sizes, int n_in,
                              void* d_out, int out_size, void* d_ws, size_t ws_size,
                              hipStream_t stream) {
    const float* s = (const float*)d_in[0];
    const float* t = (const float*)d_in[1];
    float* out = (float*)d_out;

    const size_t elems = (size_t)B_DIM * N_DIM * L_DIM * D_IN;   // 2,064,384
    const size_t need  = 2 * elems * sizeof(float);              // ~16.5 MB

    if (d_ws != nullptr && ws_size >= need) {
        float* so = (float*)d_ws;
        float* to = so + elems;
        hipLaunchKernelGGL(transpose_kernel, dim3(2 * B_DIM * N_DIM), dim3(256), 0, stream,
                           s, t, so, to);
        // grid: q*512 + (b*16 + j) = 2048 workgroups x 256 threads (4 waves)
        hipLaunchKernelGGL(conv_kernel_v7, dim3(B_DIM * N_DIM * 4), dim3(256), 0, stream,
                           so, to, out);
    } else {
        hipLaunchKernelGGL(conv_kernel_fallback, dim3(B_DIM * N_DIM * N_DIM), dim3(64), 0, stream,
                           s, t, out);
    }
}